// Round 11
// baseline (512.287 us; speedup 1.0000x reference)
//
#include <hip/hip_runtime.h>
#include <hip/hip_bf16.h>

#define NB 2
#define NT 8
#define NHW 576
#define NC 192
#define DIN 384
#define NSTATE 16
#define MTOK 9216   /* NB*NT*NHW */
#define MLPH 768
#define SCH 36      /* spatial scan chunks */
#define CLEN 16     /* 576 / 36 */
#define NSEQ_S 16   /* NB*NT */
#define L2E 1.44269504088896f
#define LN2 0.69314718055994f

typedef const __hip_bfloat16* bf16p;
typedef __hip_bfloat16 bf16;

typedef __attribute__((ext_vector_type(8))) short frag_ab;   // 8 bf16 (4 VGPRs)
typedef __attribute__((ext_vector_type(4))) float frag_cd;   // 4 f32 acc

__device__ __forceinline__ float b2f(__hip_bfloat16 x) { return __bfloat162float(x); }
__device__ __forceinline__ bf16 f2b(float x) { return __float2bfloat16(x); }

// dual-dtype load from an EXTERNAL tensor: f32 if flag, else bf16
__device__ __forceinline__ float ldv(const void* p, long long i, bool f32) {
    return f32 ? ((const float*)p)[i] : b2f(((const bf16*)p)[i]);
}

__device__ __forceinline__ float siluf(float x) { return x / (1.f + expf(-x)); }
// native v_exp/v_log softplus: max(x,0) + log2(1+exp2(-|x|*L2E))*ln2
__device__ __forceinline__ float softplus_fast(float x) {
    float e = exp2f(-fabsf(x) * L2E);
    return fmaxf(x, 0.f) + log2f(1.f + e) * LN2;
}
__device__ __forceinline__ float geluf(float x) { return 0.5f * x * (1.f + erff(x * 0.7071067811865476f)); }

// ---------------------------------------------------------------------------
__global__ void detect_kernel(const unsigned* __restrict__ n1w, int* __restrict__ flag) {
    if (threadIdx.x == 0 && blockIdx.x == 0)
        *flag = (n1w[0] == 0x3F800000u) ? 1 : 0;
}

// ---------------------------------------------------------------------------
// LN1 with [B,T,C,H,W] -> [B*T*N, C] transpose, LDS-transposed for coalescing.
// block = 256 (4 waves), grid = 16 bt * 9 hw-tiles = 144.
__global__ __launch_bounds__(256) void ln1_kernel(const void* x_in, const void* w, const void* b,
                                                  bf16* __restrict__ xn,
                                                  bf16* __restrict__ shortcut,
                                                  const int* __restrict__ flag) {
    bool f32 = (*flag != 0);
    int bt = blockIdx.x / 9;
    int hw0 = (blockIdx.x % 9) * 64;
    int t = threadIdx.x, l = t & 63, wv = t >> 6;
    __shared__ bf16 lv[192 * 66];           // [c][hw], stride 66 (conflict-free)
    __shared__ float psum[4][64], psq[4][64];
    __shared__ float smean[64], srstd[64];
    __shared__ float swl[192], sbl[192];
    for (int i = t; i < 192; i += 256) { swl[i] = ldv(w, i, f32); sbl[i] = ldv(b, i, f32); }
    float s = 0.f, q = 0.f;
#pragma unroll 4
    for (int cg = 0; cg < 48; cg++) {
        int c = wv * 48 + cg;
        float v = ldv(x_in, (long long)(bt * NC + c) * NHW + hw0 + l, f32);
        lv[c * 66 + l] = f2b(v);
        s += v; q += v * v;
    }
    psum[wv][l] = s; psq[wv][l] = q;
    __syncthreads();
    if (t < 64) {
        float ss = psum[0][t] + psum[1][t] + psum[2][t] + psum[3][t];
        float qq = psq[0][t] + psq[1][t] + psq[2][t] + psq[3][t];
        float mean = ss * (1.f / NC);
        float var = qq * (1.f / NC) - mean * mean;
        smean[t] = mean;
        srstd[t] = rsqrtf(var + 1e-5f);
    }
    __syncthreads();
    for (int jj = 0; jj < 64; jj++) {
        if (t < 192) {
            long long m = (long long)(bt * NHW + hw0 + jj) * NC + t;
            bf16 raw = lv[t * 66 + jj];
            float v = b2f(raw);
            shortcut[m] = raw;
            xn[m] = f2b((v - smean[jj]) * srstd[jj] * swl[t] + sbl[t]);
        }
    }
}

// LN2: reads f32 trunk (coalesced), writes bf16. block=64, grid=MTOK.
__device__ __forceinline__ float wave_sum(float v) {
#pragma unroll
    for (int o = 32; o > 0; o >>= 1) v += __shfl_xor(v, o, 64);
    return v;
}
__global__ __launch_bounds__(64) void ln2_kernel(const float* __restrict__ x, const void* w, const void* b,
                                                 bf16* __restrict__ out,
                                                 const int* __restrict__ flag) {
    bool f32 = (*flag != 0);
    int m = blockIdx.x;
    int lane = threadIdx.x;
    float v[3];
#pragma unroll
    for (int r = 0; r < 3; r++) v[r] = x[m * NC + lane + r * 64];
    float s = wave_sum(v[0] + v[1] + v[2]);
    float mean = s * (1.f / NC);
    float q = 0.f;
#pragma unroll
    for (int r = 0; r < 3; r++) { float d = v[r] - mean; q += d * d; }
    q = wave_sum(q);
    float rstd = rsqrtf(q * (1.f / NC) + 1e-5f);
#pragma unroll
    for (int r = 0; r < 3; r++) {
        int c = lane + r * 64;
        out[m * NC + c] = f2b((v[r] - mean) * rstd * ldv(w, c, f32) + ldv(b, c, f32));
    }
}

// ---------------------------------------------------------------------------
__device__ __forceinline__ void store_val(float* p, float v) { *p = v; }
__device__ __forceinline__ void store_val(bf16* p, float v) { *p = f2b(v); }
__device__ __forceinline__ float load_val(const float* p) { return *p; }
__device__ __forceinline__ float load_val(const bf16* p) { return b2f(*p); }

// ---------------------------------------------------------------------------
// MFMA GEMM with XCD-aware grid order + register double-buffered staging.
// grid = dim3(M/128, N/64): bid = mt + (M/128)*nt; M/128=72 ≡ 0 mod 8, so all
// n-tiles of one m-tile share bid%8 -> same XCD -> A-tile fetched once per L2.
#define LDSTR 40
template <int ACT, int FMODE, bool BCHK, typename OutT, typename AddT>
__global__ __launch_bounds__(256) void gemm_mfma(bf16p A, const void* W, const void* bias,
                                                 const AddT* __restrict__ addsrc,
                                                 OutT* __restrict__ out,
                                                 int M, int N, int K,
                                                 const int* __restrict__ flag) {
    bool f32 = (*flag != 0);
    __shared__ bf16 lds_a[128 * LDSTR];
    __shared__ bf16 lds_b[64 * LDSTR];
    int tid = threadIdx.x;
    int m0 = blockIdx.x * 128, n0 = blockIdx.y * 64;
    int wv = tid >> 6;
    int lane = tid & 63;
    int lr = lane & 15;
    int quad = lane >> 4;
    int wm = (wv >> 1) * 64;
    int wn = (wv & 1) * 32;
    int arow = tid >> 2, acol = (tid & 3) * 8;     // this thread's A stage slot (p=0)
    int brow = tid >> 2, bcol = (tid & 3) * 8;     // B stage slot
    bool bok = !BCHK || (n0 + brow) < N;

    frag_cd acc[4][2] = {};
    uint4 ra[2], rb;

    // prefetch tile 0 into registers
#pragma unroll
    for (int p = 0; p < 2; p++)
        ra[p] = *(const uint4*)&A[(size_t)(m0 + arow + p * 64) * K + acol];
    if (!bok) {
        rb = uint4{0, 0, 0, 0};
    } else if (f32) {
        union { uint4 v; bf16 h[8]; } u;
        const float* Wf = (const float*)W;
#pragma unroll
        for (int j = 0; j < 8; j++) u.h[j] = f2b(Wf[(size_t)(n0 + brow) * K + bcol + j]);
        rb = u.v;
    } else {
        rb = *(const uint4*)&((const bf16*)W)[(size_t)(n0 + brow) * K + bcol];
    }

    for (int kc = 0; kc < K; kc += 32) {
        // commit staged registers to LDS
#pragma unroll
        for (int p = 0; p < 2; p++)
            *(uint4*)&lds_a[(arow + p * 64) * LDSTR + acol] = ra[p];
        *(uint4*)&lds_b[brow * LDSTR + bcol] = rb;
        __syncthreads();

        // prefetch next tile (overlaps ds_read + MFMA below)
        int kn = kc + 32;
        if (kn < K) {
#pragma unroll
            for (int p = 0; p < 2; p++)
                ra[p] = *(const uint4*)&A[(size_t)(m0 + arow + p * 64) * K + kn + acol];
            if (!bok) {
                rb = uint4{0, 0, 0, 0};
            } else if (f32) {
                union { uint4 v; bf16 h[8]; } u;
                const float* Wf = (const float*)W;
#pragma unroll
                for (int j = 0; j < 8; j++) u.h[j] = f2b(Wf[(size_t)(n0 + brow) * K + kn + bcol + j]);
                rb = u.v;
            } else {
                rb = *(const uint4*)&((const bf16*)W)[(size_t)(n0 + brow) * K + kn + bcol];
            }
        }

        frag_ab af[4], bfr[2];
#pragma unroll
        for (int tm = 0; tm < 4; tm++)
            af[tm] = *(const frag_ab*)&lds_a[(wm + tm * 16 + lr) * LDSTR + quad * 8];
#pragma unroll
        for (int tn = 0; tn < 2; tn++)
            bfr[tn] = *(const frag_ab*)&lds_b[(wn + tn * 16 + lr) * LDSTR + quad * 8];
#pragma unroll
        for (int tm = 0; tm < 4; tm++)
#pragma unroll
            for (int tn = 0; tn < 2; tn++)
                acc[tm][tn] = __builtin_amdgcn_mfma_f32_16x16x32_bf16(
                    af[tm], bfr[tn], acc[tm][tn], 0, 0, 0);
        __syncthreads();
    }

    // epilogue: D layout col=lane&15, row=quad*4+reg
#pragma unroll
    for (int tm = 0; tm < 4; tm++) {
#pragma unroll
        for (int r = 0; r < 4; r++) {
            int gm = m0 + wm + tm * 16 + quad * 4 + r;
            long long rowbase;
            if (FMODE == 0) {
                rowbase = (long long)gm * N;
            } else if (FMODE == 1) {
                rowbase = (long long)gm * 384;
            } else {
                int b = gm / (NHW * NT);
                int rr = gm % (NHW * NT);
                int n = rr / NT;
                int t = rr % NT;
                int ms = (b * NT + t) * NHW + n;
                rowbase = (long long)ms * 384 + 192;
            }
#pragma unroll
            for (int tn = 0; tn < 2; tn++) {
                int gn = n0 + wn + tn * 16 + lr;
                if (BCHK && gn >= N) continue;
                float v = acc[tm][tn][r];
                if (bias) v += ldv(bias, gn, f32);
                if (ACT == 1) v = geluf(v);
                if (addsrc) v += load_val(&addsrc[(long long)gm * N + gn]);
                store_val(&out[rowbase + gn], v);
            }
        }
    }
}

// ---------------------------------------------------------------------------
// Causal depthwise conv (k=4) + bias + silu.
__global__ __launch_bounds__(256) void conv_kernel(bf16p xz, const void* cw, const void* cb,
                                                   bf16* __restrict__ xm,
                                                   int nseq, int L,
                                                   const int* __restrict__ flag) {
    bool f32 = (*flag != 0);
    int idx = blockIdx.x * blockDim.x + threadIdx.x;
    int total = nseq * L * DIN;
    if (idx >= total) return;
    int d = idx % DIN;
    int rem = idx / DIN;
    int l = rem % L;
    int seq = rem / L;
    float s = ldv(cb, d, f32);
#pragma unroll
    for (int k = 0; k < 4; k++) {
        int ll = l - 3 + k;
        if (ll >= 0) s += ldv(cw, d * 4 + k, f32) * b2f(xz[(long long)(seq * L + ll) * 768 + d]);
    }
    xm[(long long)(seq * L + l) * DIN + d] = f2b(siluf(s));
}

// ---------------------------------------------------------------------------
// Serial selective scan (temporal, L=8), unrolled + LDS dbc + reg prefetch.
template <int TL>
__global__ __launch_bounds__(128) void scan_kernel(bf16p xm,
                                                   const float* __restrict__ dbc,
                                                   bf16p xz,
                                                   const void* dtw, const void* dtb,
                                                   const void* A_log, const void* Dv,
                                                   bf16* __restrict__ ys,
                                                   const int* __restrict__ flag) {
    bool f32 = (*flag != 0);
    int seq = blockIdx.x / 3;
    int d = (blockIdx.x % 3) * 128 + threadIdx.x;
    int row0 = seq * TL;
    __shared__ float sdbc[TL * 44];
    for (int i = threadIdx.x; i < TL * 44; i += 128)
        sdbc[i] = dbc[(long long)row0 * 44 + i];
    bf16 um[TL], zm[TL];
#pragma unroll
    for (int t = 0; t < TL; t++) {
        um[t] = xm[(long long)(row0 + t) * DIN + d];
        zm[t] = xz[(long long)(row0 + t) * 768 + DIN + d];
    }
    float A2[NSTATE], h[NSTATE];
#pragma unroll
    for (int n = 0; n < NSTATE; n++) {
        A2[n] = -expf(ldv(A_log, d * NSTATE + n, f32)) * L2E;
        h[n] = 0.f;
    }
    float wdt[12];
#pragma unroll
    for (int r = 0; r < 12; r++) wdt[r] = ldv(dtw, d * 12 + r, f32);
    float bdt = ldv(dtb, d, f32);
    float Dd = ldv(Dv, d, f32);
    __syncthreads();
#pragma unroll
    for (int t = 0; t < TL; t++) {
        const float* dr = &sdbc[t * 44];
        float s = bdt;
#pragma unroll
        for (int r = 0; r < 12; r++) s += dr[r] * wdt[r];
        float dv = softplus_fast(s);
        float uv = b2f(um[t]);
        float du = dv * uv;
        float y = 0.f;
#pragma unroll
        for (int n = 0; n < NSTATE; n++) {
            float dA = exp2f(dv * A2[n]);
            h[n] = h[n] * dA + du * dr[12 + n];
            y += h[n] * dr[28 + n];
        }
        y += uv * Dd;
        ys[(long long)(row0 + t) * DIN + d] = f2b(y * siluf(b2f(zm[t])));
    }
}

// ---------------------------------------------------------------------------
// Chunked spatial scan pass 1 (split-state). Computes delta once (fast
// softplus), stores bf16 delta into ysdelta[] (= YS overlay) for scan3 reuse.
__global__ __launch_bounds__(256) void scan1_kernel(bf16p xm,
                                                    const float* __restrict__ dbc,
                                                    const void* dtw, const void* dtb,
                                                    const void* A_log,
                                                    bf16* __restrict__ hfin,
                                                    float* __restrict__ dsumb,
                                                    bf16* __restrict__ ysdelta,
                                                    const int* __restrict__ flag) {
    bool f32 = (*flag != 0);
    int bid = blockIdx.x;
    int part = bid % 3;
    int ch = (bid / 3) % SCH;
    int seq = bid / (3 * SCH);
    int tid = threadIdx.x;
    int wave = tid >> 6;
    int lane = tid & 63;
    int dl = lane & 31;
    int nh = lane >> 5;
    int d = part * 128 + wave * 32 + dl;
    int nbase = nh * 8;
    int row0 = seq * NHW + ch * CLEN;
    __shared__ float sdbc[CLEN * 44];
    for (int i = tid; i < CLEN * 44; i += 256)
        sdbc[i] = dbc[(long long)row0 * 44 + i];
    bf16 um[CLEN];
#pragma unroll
    for (int t = 0; t < CLEN; t++)
        um[t] = xm[(long long)(row0 + t) * DIN + d];
    float A2[8], h[8];
#pragma unroll
    for (int j = 0; j < 8; j++) {
        A2[j] = -expf(ldv(A_log, d * NSTATE + nbase + j, f32)) * L2E;
        h[j] = 0.f;
    }
    float wdt[12];
#pragma unroll
    for (int r = 0; r < 12; r++) wdt[r] = ldv(dtw, d * 12 + r, f32);
    float bdt = ldv(dtb, d, f32);
    float dsum = 0.f;
    __syncthreads();
#pragma unroll
    for (int t = 0; t < CLEN; t++) {
        const float* dr = &sdbc[t * 44];
        float s = bdt;
#pragma unroll
        for (int r = 0; r < 12; r++) s += dr[r] * wdt[r];
        bf16 dvb = f2b(softplus_fast(s));
        float dv = b2f(dvb);                  // round so scan3 evolves identically
        if (nh == 0) ysdelta[(long long)(row0 + t) * DIN + d] = dvb;
        dsum += dv;
        float du = dv * b2f(um[t]);
#pragma unroll
        for (int j = 0; j < 8; j++) {
            float dA = exp2f(dv * A2[j]);
            h[j] = h[j] * dA + du * dr[12 + nbase + j];
        }
    }
    long long base = (((long long)seq * SCH + ch) * DIN + d) * NSTATE + nbase;
#pragma unroll
    for (int j = 0; j < 8; j++) hfin[base + j] = f2b(h[j]);
    if (nh == 0) dsumb[((long long)seq * SCH + ch) * DIN + d] = dsum;
}

// Pass 2: combine chunk summaries. p = exp(dsum*A) recomputed from A_log.
__global__ __launch_bounds__(256) void scan2_kernel(bf16* __restrict__ hfin,
                                                    const float* __restrict__ dsumb,
                                                    const void* A_log,
                                                    const int* __restrict__ flag) {
    bool f32 = (*flag != 0);
    int e = blockIdx.x * blockDim.x + threadIdx.x;
    int seq = e / (DIN * NSTATE);
    int dn = e % (DIN * NSTATE);
    int d = dn >> 4;
    float A2 = -expf(ldv(A_log, dn, f32)) * L2E;
    float hrun = 0.f;
    for (int ch = 0; ch < SCH; ch++) {
        long long cidx = (long long)seq * SCH + ch;
        float p = exp2f(dsumb[cidx * DIN + d] * A2);
        long long idx = cidx * (DIN * NSTATE) + dn;
        float hf = b2f(hfin[idx]);
        hfin[idx] = f2b(hrun);
        hrun = p * hrun + hf;
    }
}

// Pass 3 (split-state): re-run chunk from true h_init, delta pre-loaded from
// ysdelta (no projection/softplus here), then overwrite ys with gated output.
__global__ __launch_bounds__(256) void scan3_kernel(bf16p xm,
                                                    const float* __restrict__ dbc,
                                                    bf16p xz,
                                                    const void* A_log, const void* Dv,
                                                    const bf16* __restrict__ hinit,
                                                    bf16* __restrict__ ys,
                                                    const int* __restrict__ flag) {
    bool f32 = (*flag != 0);
    int bid = blockIdx.x;
    int part = bid % 3;
    int ch = (bid / 3) % SCH;
    int seq = bid / (3 * SCH);
    int tid = threadIdx.x;
    int wave = tid >> 6;
    int lane = tid & 63;
    int dl = lane & 31;
    int nh = lane >> 5;
    int d = part * 128 + wave * 32 + dl;
    int nbase = nh * 8;
    int row0 = seq * NHW + ch * CLEN;
    __shared__ float sdbc[CLEN * 44];
    for (int i = tid; i < CLEN * 44; i += 256)
        sdbc[i] = dbc[(long long)row0 * 44 + i];
    bf16 um[CLEN], zm[CLEN], dm[CLEN];
#pragma unroll
    for (int t = 0; t < CLEN; t++) {
        um[t] = xm[(long long)(row0 + t) * DIN + d];
        zm[t] = xz[(long long)(row0 + t) * 768 + DIN + d];
        dm[t] = ys[(long long)(row0 + t) * DIN + d];   // delta from scan1
    }
    long long base = (((long long)seq * SCH + ch) * DIN + d) * NSTATE + nbase;
    float A2[8], h[8];
#pragma unroll
    for (int j = 0; j < 8; j++) {
        A2[j] = -expf(ldv(A_log, d * NSTATE + nbase + j, f32)) * L2E;
        h[j] = b2f(hinit[base + j]);
    }
    float Dd = ldv(Dv, d, f32);
    __syncthreads();
#pragma unroll
    for (int t = 0; t < CLEN; t++) {
        const float* dr = &sdbc[t * 44];
        float dv = b2f(dm[t]);
        float uv = b2f(um[t]);
        float du = dv * uv;
        float y = 0.f;
#pragma unroll
        for (int j = 0; j < 8; j++) {
            float dA = exp2f(dv * A2[j]);
            h[j] = h[j] * dA + du * dr[12 + nbase + j];
            y += h[j] * dr[28 + nbase + j];
        }
        y += __shfl_xor(y, 32, 64);
        if (nh == 0) {
            y += uv * Dd;
            ys[(long long)(row0 + t) * DIN + d] = f2b(y * siluf(b2f(zm[t])));
        }
    }
}

// ---------------------------------------------------------------------------
__global__ __launch_bounds__(256) void transpose_kernel(bf16p xn, bf16* __restrict__ xnt) {
    int idx = blockIdx.x * blockDim.x + threadIdx.x;
    if (idx >= MTOK * NC) return;
    int c = idx % NC;
    int mt = idx / NC;
    int b = mt / (NHW * NT);
    int r = mt % (NHW * NT);
    int n = r / NT;
    int t = r % NT;
    int ms = (b * NT + t) * NHW + n;
    xnt[idx] = xn[(long long)ms * NC + c];
}

// ---------------------------------------------------------------------------
// final [B*T*N, C] f32 -> out [B,T,C,H,W], LDS-transposed (coalesced both sides).
__global__ __launch_bounds__(256) void out_kernel(const float* __restrict__ fin,
                                                  void* __restrict__ out,
                                                  const int* __restrict__ flag) {
    bool f32 = (*flag != 0);
    int bt = blockIdx.x / 9;
    int hw0 = (blockIdx.x % 9) * 64;
    int t = threadIdx.x, l = t & 63, wv = t >> 6;
    __shared__ float lf[192 * 67];          // [c][hw], stride 67 (2-way max)
    for (int jj = 0; jj < 64; jj++) {
        if (t < 192)
            lf[t * 67 + jj] = fin[(long long)(bt * NHW + hw0 + jj) * NC + t];
    }
    __syncthreads();
#pragma unroll 4
    for (int cg = 0; cg < 48; cg++) {
        int c = wv * 48 + cg;
        float v = lf[c * 67 + l];
        long long o = (long long)(bt * NC + c) * NHW + hw0 + l;
        if (f32) ((float*)out)[o] = v;
        else     ((bf16*)out)[o] = f2b(v);
    }
}

// ---------------------------------------------------------------------------
extern "C" void kernel_launch(void* const* d_in, const int* in_sizes, int n_in,
                              void* d_out, int out_size, void* d_ws, size_t ws_size,
                              hipStream_t stream) {
    const void* x_in   = d_in[0];
    const void* n1w    = d_in[1];
    const void* n1b    = d_in[2];
    const void* s_inw  = d_in[3];
    const void* s_cw   = d_in[4];
    const void* s_cb   = d_in[5];
    const void* s_xw   = d_in[6];
    const void* s_dtw  = d_in[7];
    const void* s_dtb  = d_in[8];
    const void* s_alog = d_in[9];
    const void* s_d    = d_in[10];
    const void* s_ow   = d_in[11];
    const void* t_inw  = d_in[12];
    const void* t_cw   = d_in[13];
    const void* t_cb   = d_in[14];
    const void* t_xw   = d_in[15];
    const void* t_dtw  = d_in[16];
    const void* t_dtb  = d_in[17];
    const void* t_alog = d_in[18];
    const void* t_d    = d_in[19];
    const void* t_ow   = d_in[20];
    const void* fw     = d_in[21];
    const void* fb     = d_in[22];
    const void* n2w    = d_in[23];
    const void* n2b    = d_in[24];
    const void* w1     = d_in[25];
    const void* b1     = d_in[26];
    const void* w2     = d_in[27];
    const void* b2     = d_in[28];

    // ---- workspace layout: identical to the round-4/6 proven-safe footprint ----
    char* p = (char*)d_ws;
    int* FLAG   = (int*)p;  p += 16;
    bf16* XN    = (bf16*)p; p += (size_t)MTOK * NC * 2;
    bf16* SHORT = (bf16*)p; p += (size_t)MTOK * NC * 2;
    bf16* XNT   = (bf16*)p; p += (size_t)MTOK * NC * 2;
    bf16* FUSED = (bf16*)p; p += (size_t)MTOK * 384 * 2;
    bf16* XZ    = (bf16*)p; p += (size_t)MTOK * 768 * 2;
    bf16* XM    = (bf16*)p; p += (size_t)MTOK * DIN * 2;
    bf16* YS    = (bf16*)p; p += (size_t)MTOK * DIN * 2;
    float* DBC  = (float*)p; p += (size_t)MTOK * 44 * 4;
    float* X2   = (float*)p; p += (size_t)MTOK * NC * 4;
    // overlays (lifetimes strictly disjoint):
    bf16*  H     = XN;
    bf16*  HMID  = XZ;
    float* FINAL = (float*)XM;
    bf16*  HFIN  = FUSED;
    float* DSUM  = (float*)X2;

    int ew_blocks_din = (MTOK * DIN + 255) / 256;
    int ew_blocks_c   = (MTOK * NC + 255) / 256;

    detect_kernel<<<1, 64, 0, stream>>>((const unsigned*)n1w, FLAG);
    ln1_kernel<<<144, 256, 0, stream>>>(x_in, n1w, n1b, XN, SHORT, FLAG);

    // ---- spatial mamba ----
    gemm_mfma<0, 0, false, bf16, float><<<dim3(MTOK / 128, 768 / 64), 256, 0, stream>>>(XN, s_inw, nullptr, nullptr, XZ, MTOK, 768, NC, FLAG);
    conv_kernel<<<ew_blocks_din, 256, 0, stream>>>(XZ, s_cw, s_cb, XM, NB * NT, NHW, FLAG);
    gemm_mfma<0, 0, true, float, float><<<dim3(MTOK / 128, 1), 256, 0, stream>>>(XM, s_xw, nullptr, nullptr, DBC, MTOK, 44, DIN, FLAG);
    scan1_kernel<<<NSEQ_S * SCH * 3, 256, 0, stream>>>(XM, DBC, s_dtw, s_dtb, s_alog, HFIN, DSUM, YS, FLAG);
    scan2_kernel<<<NSEQ_S * DIN * NSTATE / 256, 256, 0, stream>>>(HFIN, DSUM, s_alog, FLAG);
    scan3_kernel<<<NSEQ_S * SCH * 3, 256, 0, stream>>>(XM, DBC, XZ, s_alog, s_d, HFIN, YS, FLAG);
    gemm_mfma<0, 1, false, bf16, float><<<dim3(MTOK / 128, NC / 64), 256, 0, stream>>>(YS, s_ow, nullptr, nullptr, FUSED, MTOK, NC, DIN, FLAG);

    // ---- temporal mamba ----
    transpose_kernel<<<ew_blocks_c, 256, 0, stream>>>(XN, XNT);
    gemm_mfma<0, 0, false, bf16, float><<<dim3(MTOK / 128, 768 / 64), 256, 0, stream>>>(XNT, t_inw, nullptr, nullptr, XZ, MTOK, 768, NC, FLAG);
    conv_kernel<<<ew_blocks_din, 256, 0, stream>>>(XZ, t_cw, t_cb, XM, NB * NHW, NT, FLAG);
    gemm_mfma<0, 0, true, float, float><<<dim3(MTOK / 128, 1), 256, 0, stream>>>(XM, t_xw, nullptr, nullptr, DBC, MTOK, 44, DIN, FLAG);
    scan_kernel<NT><<<NB * NHW * 3, 128, 0, stream>>>(XM, DBC, XZ, t_dtw, t_dtb, t_alog, t_d, YS, FLAG);
    gemm_mfma<0, 2, false, bf16, float><<<dim3(MTOK / 128, NC / 64), 256, 0, stream>>>(YS, t_ow, nullptr, nullptr, FUSED, MTOK, NC, DIN, FLAG);

    // ---- fusion + residual ----
    gemm_mfma<0, 0, false, float, bf16><<<dim3(MTOK / 128, NC / 64), 256, 0, stream>>>(FUSED, fw, fb, SHORT, X2, MTOK, NC, 2 * NC, FLAG);

    // ---- MLP ----
    ln2_kernel<<<MTOK, 64, 0, stream>>>(X2, n2w, n2b, H, FLAG);
    gemm_mfma<1, 0, false, bf16, float><<<dim3(MTOK / 128, MLPH / 64), 256, 0, stream>>>(H, w1, b1, nullptr, HMID, MTOK, MLPH, NC, FLAG);
    gemm_mfma<0, 0, false, float, float><<<dim3(MTOK / 128, NC / 64), 256, 0, stream>>>(HMID, w2, b2, X2, FINAL, MTOK, NC, MLPH, FLAG);

    out_kernel<<<144, 256, 0, stream>>>(FINAL, d_out, FLAG);
}

// Round 12
// 510.523 us; speedup vs baseline: 1.0035x; 1.0035x over previous
//
#include <hip/hip_runtime.h>
#include <hip/hip_bf16.h>

#define NB 2
#define NT 8
#define NHW 576
#define NC 192
#define DIN 384
#define NSTATE 16
#define MTOK 9216   /* NB*NT*NHW */
#define MLPH 768
#define SCH 36      /* spatial scan chunks */
#define CLEN 16     /* 576 / 36 */
#define NSEQ_S 16   /* NB*NT */
#define L2E 1.44269504088896f
#define LN2 0.69314718055994f

typedef const __hip_bfloat16* bf16p;
typedef __hip_bfloat16 bf16;

typedef __attribute__((ext_vector_type(8))) short frag_ab;   // 8 bf16 (4 VGPRs)
typedef __attribute__((ext_vector_type(4))) float frag_cd;   // 4 f32 acc

__device__ __forceinline__ float b2f(__hip_bfloat16 x) { return __bfloat162float(x); }
__device__ __forceinline__ bf16 f2b(float x) { return __float2bfloat16(x); }

// dual-dtype load from an EXTERNAL tensor: f32 if flag, else bf16
__device__ __forceinline__ float ldv(const void* p, long long i, bool f32) {
    return f32 ? ((const float*)p)[i] : b2f(((const bf16*)p)[i]);
}

__device__ __forceinline__ float siluf(float x) { return x / (1.f + expf(-x)); }
// native v_exp/v_log softplus: max(x,0) + log2(1+exp2(-|x|*L2E))*ln2
__device__ __forceinline__ float softplus_fast(float x) {
    float e = exp2f(-fabsf(x) * L2E);
    return fmaxf(x, 0.f) + log2f(1.f + e) * LN2;
}
__device__ __forceinline__ float geluf(float x) { return 0.5f * x * (1.f + erff(x * 0.7071067811865476f)); }

// ---------------------------------------------------------------------------
__global__ void detect_kernel(const unsigned* __restrict__ n1w, int* __restrict__ flag) {
    if (threadIdx.x == 0 && blockIdx.x == 0)
        *flag = (n1w[0] == 0x3F800000u) ? 1 : 0;
}

// ---------------------------------------------------------------------------
// LN1 with [B,T,C,H,W] -> [B*T*N, C] transpose, LDS-transposed for coalescing.
__global__ __launch_bounds__(256) void ln1_kernel(const void* x_in, const void* w, const void* b,
                                                  bf16* __restrict__ xn,
                                                  bf16* __restrict__ shortcut,
                                                  const int* __restrict__ flag) {
    bool f32 = (*flag != 0);
    int bt = blockIdx.x / 9;
    int hw0 = (blockIdx.x % 9) * 64;
    int t = threadIdx.x, l = t & 63, wv = t >> 6;
    __shared__ bf16 lv[192 * 66];
    __shared__ float psum[4][64], psq[4][64];
    __shared__ float smean[64], srstd[64];
    __shared__ float swl[192], sbl[192];
    for (int i = t; i < 192; i += 256) { swl[i] = ldv(w, i, f32); sbl[i] = ldv(b, i, f32); }
    float s = 0.f, q = 0.f;
#pragma unroll 4
    for (int cg = 0; cg < 48; cg++) {
        int c = wv * 48 + cg;
        float v = ldv(x_in, (long long)(bt * NC + c) * NHW + hw0 + l, f32);
        lv[c * 66 + l] = f2b(v);
        s += v; q += v * v;
    }
    psum[wv][l] = s; psq[wv][l] = q;
    __syncthreads();
    if (t < 64) {
        float ss = psum[0][t] + psum[1][t] + psum[2][t] + psum[3][t];
        float qq = psq[0][t] + psq[1][t] + psq[2][t] + psq[3][t];
        float mean = ss * (1.f / NC);
        float var = qq * (1.f / NC) - mean * mean;
        smean[t] = mean;
        srstd[t] = rsqrtf(var + 1e-5f);
    }
    __syncthreads();
    for (int jj = 0; jj < 64; jj++) {
        if (t < 192) {
            long long m = (long long)(bt * NHW + hw0 + jj) * NC + t;
            bf16 raw = lv[t * 66 + jj];
            float v = b2f(raw);
            shortcut[m] = raw;
            xn[m] = f2b((v - smean[jj]) * srstd[jj] * swl[t] + sbl[t]);
        }
    }
}

// LN2: reads f32 trunk (coalesced), writes bf16. block=64, grid=MTOK.
__device__ __forceinline__ float wave_sum(float v) {
#pragma unroll
    for (int o = 32; o > 0; o >>= 1) v += __shfl_xor(v, o, 64);
    return v;
}
__global__ __launch_bounds__(64) void ln2_kernel(const float* __restrict__ x, const void* w, const void* b,
                                                 bf16* __restrict__ out,
                                                 const int* __restrict__ flag) {
    bool f32 = (*flag != 0);
    int m = blockIdx.x;
    int lane = threadIdx.x;
    float v[3];
#pragma unroll
    for (int r = 0; r < 3; r++) v[r] = x[m * NC + lane + r * 64];
    float s = wave_sum(v[0] + v[1] + v[2]);
    float mean = s * (1.f / NC);
    float q = 0.f;
#pragma unroll
    for (int r = 0; r < 3; r++) { float d = v[r] - mean; q += d * d; }
    q = wave_sum(q);
    float rstd = rsqrtf(q * (1.f / NC) + 1e-5f);
#pragma unroll
    for (int r = 0; r < 3; r++) {
        int c = lane + r * 64;
        out[m * NC + c] = f2b((v[r] - mean) * rstd * ldv(w, c, f32) + ldv(b, c, f32));
    }
}

// ---------------------------------------------------------------------------
__device__ __forceinline__ void store_val(float* p, float v) { *p = v; }
__device__ __forceinline__ void store_val(bf16* p, float v) { *p = f2b(v); }
__device__ __forceinline__ float load_val(const float* p) { return *p; }
__device__ __forceinline__ float load_val(const bf16* p) { return b2f(*p); }

// ---------------------------------------------------------------------------
// MFMA GEMM, BK=64: two 32-k subtiles per LDS stage -> 96 B/thread in flight
// (2x Little's-law BW vs BK=32), 16 MFMAs per barrier, K/64 iterations.
// XCD-aware grid: dim3(M/128, N/64) keeps all n-tiles of an m-tile on one XCD.
// Requires K % 64 == 0 (all our K: 192, 384, 768).
#define LDSTR 40
template <int ACT, int FMODE, bool BCHK, typename OutT, typename AddT>
__global__ __launch_bounds__(256) void gemm_mfma(bf16p A, const void* W, const void* bias,
                                                 const AddT* __restrict__ addsrc,
                                                 OutT* __restrict__ out,
                                                 int M, int N, int K,
                                                 const int* __restrict__ flag) {
    bool f32 = (*flag != 0);
    __shared__ bf16 lds_a0[128 * LDSTR];
    __shared__ bf16 lds_a1[128 * LDSTR];
    __shared__ bf16 lds_b0[64 * LDSTR];
    __shared__ bf16 lds_b1[64 * LDSTR];
    int tid = threadIdx.x;
    int m0 = blockIdx.x * 128, n0 = blockIdx.y * 64;
    int wv = tid >> 6;
    int lane = tid & 63;
    int lr = lane & 15;
    int quad = lane >> 4;
    int wm = (wv >> 1) * 64;
    int wn = (wv & 1) * 32;
    int arow = tid >> 2, acol = (tid & 3) * 8;
    int brow = tid >> 2, bcol = (tid & 3) * 8;
    bool bok = !BCHK || (n0 + brow) < N;

    frag_cd acc[4][2] = {};
    uint4 ra[4], rb[2];   // [p*2+hx] for A; [hx] for B

    auto fetchA = [&](int kc) {
#pragma unroll
        for (int p = 0; p < 2; p++)
#pragma unroll
            for (int hx = 0; hx < 2; hx++)
                ra[p * 2 + hx] = *(const uint4*)&A[(size_t)(m0 + arow + p * 64) * K + kc + hx * 32 + acol];
    };
    auto fetchB = [&](int kc) {
#pragma unroll
        for (int hx = 0; hx < 2; hx++) {
            if (!bok) {
                rb[hx] = uint4{0, 0, 0, 0};
            } else if (f32) {
                union { uint4 v; bf16 h[8]; } u;
                const float* Wf = (const float*)W;
#pragma unroll
                for (int j = 0; j < 8; j++)
                    u.h[j] = f2b(Wf[(size_t)(n0 + brow) * K + kc + hx * 32 + bcol + j]);
                rb[hx] = u.v;
            } else {
                rb[hx] = *(const uint4*)&((const bf16*)W)[(size_t)(n0 + brow) * K + kc + hx * 32 + bcol];
            }
        }
    };

    fetchA(0);
    fetchB(0);

    for (int kc = 0; kc < K; kc += 64) {
        // commit staged registers to LDS
#pragma unroll
        for (int p = 0; p < 2; p++) {
            *(uint4*)&lds_a0[(arow + p * 64) * LDSTR + acol] = ra[p * 2 + 0];
            *(uint4*)&lds_a1[(arow + p * 64) * LDSTR + acol] = ra[p * 2 + 1];
        }
        *(uint4*)&lds_b0[brow * LDSTR + bcol] = rb[0];
        *(uint4*)&lds_b1[brow * LDSTR + bcol] = rb[1];
        __syncthreads();

        int kn = kc + 64;
        if (kn < K) { fetchA(kn); fetchB(kn); }   // overlaps ds_read + MFMA

        frag_ab af[4], bfr[2];
        // subtile 0
#pragma unroll
        for (int tm = 0; tm < 4; tm++)
            af[tm] = *(const frag_ab*)&lds_a0[(wm + tm * 16 + lr) * LDSTR + quad * 8];
#pragma unroll
        for (int tn = 0; tn < 2; tn++)
            bfr[tn] = *(const frag_ab*)&lds_b0[(wn + tn * 16 + lr) * LDSTR + quad * 8];
#pragma unroll
        for (int tm = 0; tm < 4; tm++)
#pragma unroll
            for (int tn = 0; tn < 2; tn++)
                acc[tm][tn] = __builtin_amdgcn_mfma_f32_16x16x32_bf16(
                    af[tm], bfr[tn], acc[tm][tn], 0, 0, 0);
        // subtile 1
#pragma unroll
        for (int tm = 0; tm < 4; tm++)
            af[tm] = *(const frag_ab*)&lds_a1[(wm + tm * 16 + lr) * LDSTR + quad * 8];
#pragma unroll
        for (int tn = 0; tn < 2; tn++)
            bfr[tn] = *(const frag_ab*)&lds_b1[(wn + tn * 16 + lr) * LDSTR + quad * 8];
#pragma unroll
        for (int tm = 0; tm < 4; tm++)
#pragma unroll
            for (int tn = 0; tn < 2; tn++)
                acc[tm][tn] = __builtin_amdgcn_mfma_f32_16x16x32_bf16(
                    af[tm], bfr[tn], acc[tm][tn], 0, 0, 0);
        __syncthreads();
    }

    // epilogue: D layout col=lane&15, row=quad*4+reg
#pragma unroll
    for (int tm = 0; tm < 4; tm++) {
#pragma unroll
        for (int r = 0; r < 4; r++) {
            int gm = m0 + wm + tm * 16 + quad * 4 + r;
            long long rowbase;
            if (FMODE == 0) {
                rowbase = (long long)gm * N;
            } else if (FMODE == 1) {
                rowbase = (long long)gm * 384;
            } else {
                int b = gm / (NHW * NT);
                int rr = gm % (NHW * NT);
                int n = rr / NT;
                int t = rr % NT;
                int ms = (b * NT + t) * NHW + n;
                rowbase = (long long)ms * 384 + 192;
            }
#pragma unroll
            for (int tn = 0; tn < 2; tn++) {
                int gn = n0 + wn + tn * 16 + lr;
                if (BCHK && gn >= N) continue;
                float v = acc[tm][tn][r];
                if (bias) v += ldv(bias, gn, f32);
                if (ACT == 1) v = geluf(v);
                if (addsrc) v += load_val(&addsrc[(long long)gm * N + gn]);
                store_val(&out[rowbase + gn], v);
            }
        }
    }
}

// ---------------------------------------------------------------------------
// Causal depthwise conv (k=4) + bias + silu.
__global__ __launch_bounds__(256) void conv_kernel(bf16p xz, const void* cw, const void* cb,
                                                   bf16* __restrict__ xm,
                                                   int nseq, int L,
                                                   const int* __restrict__ flag) {
    bool f32 = (*flag != 0);
    int idx = blockIdx.x * blockDim.x + threadIdx.x;
    int total = nseq * L * DIN;
    if (idx >= total) return;
    int d = idx % DIN;
    int rem = idx / DIN;
    int l = rem % L;
    int seq = rem / L;
    float s = ldv(cb, d, f32);
#pragma unroll
    for (int k = 0; k < 4; k++) {
        int ll = l - 3 + k;
        if (ll >= 0) s += ldv(cw, d * 4 + k, f32) * b2f(xz[(long long)(seq * L + ll) * 768 + d]);
    }
    xm[(long long)(seq * L + l) * DIN + d] = f2b(siluf(s));
}

// ---------------------------------------------------------------------------
// Serial selective scan (temporal, L=8), unrolled + LDS dbc + reg prefetch.
template <int TL>
__global__ __launch_bounds__(128) void scan_kernel(bf16p xm,
                                                   const float* __restrict__ dbc,
                                                   bf16p xz,
                                                   const void* dtw, const void* dtb,
                                                   const void* A_log, const void* Dv,
                                                   bf16* __restrict__ ys,
                                                   const int* __restrict__ flag) {
    bool f32 = (*flag != 0);
    int seq = blockIdx.x / 3;
    int d = (blockIdx.x % 3) * 128 + threadIdx.x;
    int row0 = seq * TL;
    __shared__ float sdbc[TL * 44];
    for (int i = threadIdx.x; i < TL * 44; i += 128)
        sdbc[i] = dbc[(long long)row0 * 44 + i];
    bf16 um[TL], zm[TL];
#pragma unroll
    for (int t = 0; t < TL; t++) {
        um[t] = xm[(long long)(row0 + t) * DIN + d];
        zm[t] = xz[(long long)(row0 + t) * 768 + DIN + d];
    }
    float A2[NSTATE], h[NSTATE];
#pragma unroll
    for (int n = 0; n < NSTATE; n++) {
        A2[n] = -expf(ldv(A_log, d * NSTATE + n, f32)) * L2E;
        h[n] = 0.f;
    }
    float wdt[12];
#pragma unroll
    for (int r = 0; r < 12; r++) wdt[r] = ldv(dtw, d * 12 + r, f32);
    float bdt = ldv(dtb, d, f32);
    float Dd = ldv(Dv, d, f32);
    __syncthreads();
#pragma unroll
    for (int t = 0; t < TL; t++) {
        const float* dr = &sdbc[t * 44];
        float s = bdt;
#pragma unroll
        for (int r = 0; r < 12; r++) s += dr[r] * wdt[r];
        float dv = softplus_fast(s);
        float uv = b2f(um[t]);
        float du = dv * uv;
        float y = 0.f;
#pragma unroll
        for (int n = 0; n < NSTATE; n++) {
            float dA = exp2f(dv * A2[n]);
            h[n] = h[n] * dA + du * dr[12 + n];
            y += h[n] * dr[28 + n];
        }
        y += uv * Dd;
        ys[(long long)(row0 + t) * DIN + d] = f2b(y * siluf(b2f(zm[t])));
    }
}

// ---------------------------------------------------------------------------
// Chunked spatial scan pass 1 (split-state). Computes delta once (fast
// softplus), stores bf16 delta into ysdelta[] (= YS overlay) for scan3 reuse.
__global__ __launch_bounds__(256) void scan1_kernel(bf16p xm,
                                                    const float* __restrict__ dbc,
                                                    const void* dtw, const void* dtb,
                                                    const void* A_log,
                                                    bf16* __restrict__ hfin,
                                                    float* __restrict__ dsumb,
                                                    bf16* __restrict__ ysdelta,
                                                    const int* __restrict__ flag) {
    bool f32 = (*flag != 0);
    int bid = blockIdx.x;
    int part = bid % 3;
    int ch = (bid / 3) % SCH;
    int seq = bid / (3 * SCH);
    int tid = threadIdx.x;
    int wave = tid >> 6;
    int lane = tid & 63;
    int dl = lane & 31;
    int nh = lane >> 5;
    int d = part * 128 + wave * 32 + dl;
    int nbase = nh * 8;
    int row0 = seq * NHW + ch * CLEN;
    __shared__ float sdbc[CLEN * 44];
    for (int i = tid; i < CLEN * 44; i += 256)
        sdbc[i] = dbc[(long long)row0 * 44 + i];
    bf16 um[CLEN];
#pragma unroll
    for (int t = 0; t < CLEN; t++)
        um[t] = xm[(long long)(row0 + t) * DIN + d];
    float A2[8], h[8];
#pragma unroll
    for (int j = 0; j < 8; j++) {
        A2[j] = -expf(ldv(A_log, d * NSTATE + nbase + j, f32)) * L2E;
        h[j] = 0.f;
    }
    float wdt[12];
#pragma unroll
    for (int r = 0; r < 12; r++) wdt[r] = ldv(dtw, d * 12 + r, f32);
    float bdt = ldv(dtb, d, f32);
    float dsum = 0.f;
    __syncthreads();
#pragma unroll
    for (int t = 0; t < CLEN; t++) {
        const float* dr = &sdbc[t * 44];
        float s = bdt;
#pragma unroll
        for (int r = 0; r < 12; r++) s += dr[r] * wdt[r];
        bf16 dvb = f2b(softplus_fast(s));
        float dv = b2f(dvb);                  // round so scan3 evolves identically
        if (nh == 0) ysdelta[(long long)(row0 + t) * DIN + d] = dvb;
        dsum += dv;
        float du = dv * b2f(um[t]);
#pragma unroll
        for (int j = 0; j < 8; j++) {
            float dA = exp2f(dv * A2[j]);
            h[j] = h[j] * dA + du * dr[12 + nbase + j];
        }
    }
    long long base = (((long long)seq * SCH + ch) * DIN + d) * NSTATE + nbase;
#pragma unroll
    for (int j = 0; j < 8; j++) hfin[base + j] = f2b(h[j]);
    if (nh == 0) dsumb[((long long)seq * SCH + ch) * DIN + d] = dsum;
}

// Pass 2: combine chunk summaries. p = exp(dsum*A) recomputed from A_log.
__global__ __launch_bounds__(256) void scan2_kernel(bf16* __restrict__ hfin,
                                                    const float* __restrict__ dsumb,
                                                    const void* A_log,
                                                    const int* __restrict__ flag) {
    bool f32 = (*flag != 0);
    int e = blockIdx.x * blockDim.x + threadIdx.x;
    int seq = e / (DIN * NSTATE);
    int dn = e % (DIN * NSTATE);
    int d = dn >> 4;
    float A2 = -expf(ldv(A_log, dn, f32)) * L2E;
    float hrun = 0.f;
    for (int ch = 0; ch < SCH; ch++) {
        long long cidx = (long long)seq * SCH + ch;
        float p = exp2f(dsumb[cidx * DIN + d] * A2);
        long long idx = cidx * (DIN * NSTATE) + dn;
        float hf = b2f(hfin[idx]);
        hfin[idx] = f2b(hrun);
        hrun = p * hrun + hf;
    }
}

// Pass 3 (split-state): re-run chunk from true h_init, delta pre-loaded from
// ysdelta (no projection/softplus here), then overwrite ys with gated output.
__global__ __launch_bounds__(256) void scan3_kernel(bf16p xm,
                                                    const float* __restrict__ dbc,
                                                    bf16p xz,
                                                    const void* A_log, const void* Dv,
                                                    const bf16* __restrict__ hinit,
                                                    bf16* __restrict__ ys,
                                                    const int* __restrict__ flag) {
    bool f32 = (*flag != 0);
    int bid = blockIdx.x;
    int part = bid % 3;
    int ch = (bid / 3) % SCH;
    int seq = bid / (3 * SCH);
    int tid = threadIdx.x;
    int wave = tid >> 6;
    int lane = tid & 63;
    int dl = lane & 31;
    int nh = lane >> 5;
    int d = part * 128 + wave * 32 + dl;
    int nbase = nh * 8;
    int row0 = seq * NHW + ch * CLEN;
    __shared__ float sdbc[CLEN * 44];
    for (int i = tid; i < CLEN * 44; i += 256)
        sdbc[i] = dbc[(long long)row0 * 44 + i];
    bf16 um[CLEN], zm[CLEN], dm[CLEN];
#pragma unroll
    for (int t = 0; t < CLEN; t++) {
        um[t] = xm[(long long)(row0 + t) * DIN + d];
        zm[t] = xz[(long long)(row0 + t) * 768 + DIN + d];
        dm[t] = ys[(long long)(row0 + t) * DIN + d];   // delta from scan1
    }
    long long base = (((long long)seq * SCH + ch) * DIN + d) * NSTATE + nbase;
    float A2[8], h[8];
#pragma unroll
    for (int j = 0; j < 8; j++) {
        A2[j] = -expf(ldv(A_log, d * NSTATE + nbase + j, f32)) * L2E;
        h[j] = b2f(hinit[base + j]);
    }
    float Dd = ldv(Dv, d, f32);
    __syncthreads();
#pragma unroll
    for (int t = 0; t < CLEN; t++) {
        const float* dr = &sdbc[t * 44];
        float dv = b2f(dm[t]);
        float uv = b2f(um[t]);
        float du = dv * uv;
        float y = 0.f;
#pragma unroll
        for (int j = 0; j < 8; j++) {
            float dA = exp2f(dv * A2[j]);
            h[j] = h[j] * dA + du * dr[12 + nbase + j];
            y += h[j] * dr[28 + nbase + j];
        }
        y += __shfl_xor(y, 32, 64);
        if (nh == 0) {
            y += uv * Dd;
            ys[(long long)(row0 + t) * DIN + d] = f2b(y * siluf(b2f(zm[t])));
        }
    }
}

// ---------------------------------------------------------------------------
__global__ __launch_bounds__(256) void transpose_kernel(bf16p xn, bf16* __restrict__ xnt) {
    int idx = blockIdx.x * blockDim.x + threadIdx.x;
    if (idx >= MTOK * NC) return;
    int c = idx % NC;
    int mt = idx / NC;
    int b = mt / (NHW * NT);
    int r = mt % (NHW * NT);
    int n = r / NT;
    int t = r % NT;
    int ms = (b * NT + t) * NHW + n;
    xnt[idx] = xn[(long long)ms * NC + c];
}

// ---------------------------------------------------------------------------
// final [B*T*N, C] f32 -> out [B,T,C,H,W], LDS-transposed (coalesced both sides).
__global__ __launch_bounds__(256) void out_kernel(const float* __restrict__ fin,
                                                  void* __restrict__ out,
                                                  const int* __restrict__ flag) {
    bool f32 = (*flag != 0);
    int bt = blockIdx.x / 9;
    int hw0 = (blockIdx.x % 9) * 64;
    int t = threadIdx.x, l = t & 63, wv = t >> 6;
    __shared__ float lf[192 * 67];
    for (int jj = 0; jj < 64; jj++) {
        if (t < 192)
            lf[t * 67 + jj] = fin[(long long)(bt * NHW + hw0 + jj) * NC + t];
    }
    __syncthreads();
#pragma unroll 4
    for (int cg = 0; cg < 48; cg++) {
        int c = wv * 48 + cg;
        float v = lf[c * 67 + l];
        long long o = (long long)(bt * NC + c) * NHW + hw0 + l;
        if (f32) ((float*)out)[o] = v;
        else     ((bf16*)out)[o] = f2b(v);
    }
}

// ---------------------------------------------------------------------------
extern "C" void kernel_launch(void* const* d_in, const int* in_sizes, int n_in,
                              void* d_out, int out_size, void* d_ws, size_t ws_size,
                              hipStream_t stream) {
    const void* x_in   = d_in[0];
    const void* n1w    = d_in[1];
    const void* n1b    = d_in[2];
    const void* s_inw  = d_in[3];
    const void* s_cw   = d_in[4];
    const void* s_cb   = d_in[5];
    const void* s_xw   = d_in[6];
    const void* s_dtw  = d_in[7];
    const void* s_dtb  = d_in[8];
    const void* s_alog = d_in[9];
    const void* s_d    = d_in[10];
    const void* s_ow   = d_in[11];
    const void* t_inw  = d_in[12];
    const void* t_cw   = d_in[13];
    const void* t_cb   = d_in[14];
    const void* t_xw   = d_in[15];
    const void* t_dtw  = d_in[16];
    const void* t_dtb  = d_in[17];
    const void* t_alog = d_in[18];
    const void* t_d    = d_in[19];
    const void* t_ow   = d_in[20];
    const void* fw     = d_in[21];
    const void* fb     = d_in[22];
    const void* n2w    = d_in[23];
    const void* n2b    = d_in[24];
    const void* w1     = d_in[25];
    const void* b1     = d_in[26];
    const void* w2     = d_in[27];
    const void* b2     = d_in[28];

    // ---- workspace layout: identical to the round-4/6 proven-safe footprint ----
    char* p = (char*)d_ws;
    int* FLAG   = (int*)p;  p += 16;
    bf16* XN    = (bf16*)p; p += (size_t)MTOK * NC * 2;
    bf16* SHORT = (bf16*)p; p += (size_t)MTOK * NC * 2;
    bf16* XNT   = (bf16*)p; p += (size_t)MTOK * NC * 2;
    bf16* FUSED = (bf16*)p; p += (size_t)MTOK * 384 * 2;
    bf16* XZ    = (bf16*)p; p += (size_t)MTOK * 768 * 2;
    bf16* XM    = (bf16*)p; p += (size_t)MTOK * DIN * 2;
    bf16* YS    = (bf16*)p; p += (size_t)MTOK * DIN * 2;
    float* DBC  = (float*)p; p += (size_t)MTOK * 44 * 4;
    float* X2   = (float*)p; p += (size_t)MTOK * NC * 4;
    // overlays (lifetimes strictly disjoint):
    bf16*  H     = XN;
    bf16*  HMID  = XZ;
    float* FINAL = (float*)XM;
    bf16*  HFIN  = FUSED;
    float* DSUM  = (float*)X2;

    int ew_blocks_din = (MTOK * DIN + 255) / 256;
    int ew_blocks_c   = (MTOK * NC + 255) / 256;

    detect_kernel<<<1, 64, 0, stream>>>((const unsigned*)n1w, FLAG);
    ln1_kernel<<<144, 256, 0, stream>>>(x_in, n1w, n1b, XN, SHORT, FLAG);

    // ---- spatial mamba ----
    gemm_mfma<0, 0, false, bf16, float><<<dim3(MTOK / 128, 768 / 64), 256, 0, stream>>>(XN, s_inw, nullptr, nullptr, XZ, MTOK, 768, NC, FLAG);
    conv_kernel<<<ew_blocks_din, 256, 0, stream>>>(XZ, s_cw, s_cb, XM, NB * NT, NHW, FLAG);
    gemm_mfma<0, 0, true, float, float><<<dim3(MTOK / 128, 1), 256, 0, stream>>>(XM, s_xw, nullptr, nullptr, DBC, MTOK, 44, DIN, FLAG);
    scan1_kernel<<<NSEQ_S * SCH * 3, 256, 0, stream>>>(XM, DBC, s_dtw, s_dtb, s_alog, HFIN, DSUM, YS, FLAG);
    scan2_kernel<<<NSEQ_S * DIN * NSTATE / 256, 256, 0, stream>>>(HFIN, DSUM, s_alog, FLAG);
    scan3_kernel<<<NSEQ_S * SCH * 3, 256, 0, stream>>>(XM, DBC, XZ, s_alog, s_d, HFIN, YS, FLAG);
    gemm_mfma<0, 1, false, bf16, float><<<dim3(MTOK / 128, NC / 64), 256, 0, stream>>>(YS, s_ow, nullptr, nullptr, FUSED, MTOK, NC, DIN, FLAG);

    // ---- temporal mamba ----
    transpose_kernel<<<ew_blocks_c, 256, 0, stream>>>(XN, XNT);
    gemm_mfma<0, 0, false, bf16, float><<<dim3(MTOK / 128, 768 / 64), 256, 0, stream>>>(XNT, t_inw, nullptr, nullptr, XZ, MTOK, 768, NC, FLAG);
    conv_kernel<<<ew_blocks_din, 256, 0, stream>>>(XZ, t_cw, t_cb, XM, NB * NHW, NT, FLAG);
    gemm_mfma<0, 0, true, float, float><<<dim3(MTOK / 128, 1), 256, 0, stream>>>(XM, t_xw, nullptr, nullptr, DBC, MTOK, 44, DIN, FLAG);
    scan_kernel<NT><<<NB * NHW * 3, 128, 0, stream>>>(XM, DBC, XZ, t_dtw, t_dtb, t_alog, t_d, YS, FLAG);
    gemm_mfma<0, 2, false, bf16, float><<<dim3(MTOK / 128, NC / 64), 256, 0, stream>>>(YS, t_ow, nullptr, nullptr, FUSED, MTOK, NC, DIN, FLAG);

    // ---- fusion + residual ----
    gemm_mfma<0, 0, false, float, bf16><<<dim3(MTOK / 128, NC / 64), 256, 0, stream>>>(FUSED, fw, fb, SHORT, X2, MTOK, NC, 2 * NC, FLAG);

    // ---- MLP ----
    ln2_kernel<<<MTOK, 64, 0, stream>>>(X2, n2w, n2b, H, FLAG);
    gemm_mfma<1, 0, false, bf16, float><<<dim3(MTOK / 128, MLPH / 64), 256, 0, stream>>>(H, w1, b1, nullptr, HMID, MTOK, MLPH, NC, FLAG);
    gemm_mfma<0, 0, false, float, float><<<dim3(MTOK / 128, NC / 64), 256, 0, stream>>>(HMID, w2, b2, X2, FINAL, MTOK, NC, MLPH, FLAG);

    out_kernel<<<144, 256, 0, stream>>>(FINAL, d_out, FLAG);
}